// Round 1
// baseline (216.834 us; speedup 1.0000x reference)
//
#include <hip/hip_runtime.h>

#define N_EMB 16384
#define DIM 128
#define BM 128
#define BN 128
#define NSPLIT 4
#define CPS (N_EMB / NSPLIT)   /* columns per split = 4096 */
#define LDS_STRIDE 136         /* 128 + 8 bf16 pad: breaks bank aliasing */

typedef __bf16 bf16x8 __attribute__((ext_vector_type(8)));
typedef float f32x4 __attribute__((ext_vector_type(4)));

__device__ inline float fast_exp2(float x) {
#if __has_builtin(__builtin_amdgcn_exp2f)
  return __builtin_amdgcn_exp2f(x);
#else
  return exp2f(x);
#endif
}
__device__ inline float fast_log2(float x) {
#if __has_builtin(__builtin_amdgcn_logf)
  return __builtin_amdgcn_logf(x);
#else
  return log2f(x);
#endif
}

// fp32 -> bf16 RNE (inputs are finite, |x| < 1; no NaN handling needed)
__device__ inline unsigned short f2bf(float f) {
  unsigned int u = __float_as_uint(f);
  u += 0x7fffu + ((u >> 16) & 1u);
  return (unsigned short)(u >> 16);
}

// Stage a 128x128 fp32 tile from global into LDS as bf16, coalesced float4 loads.
__device__ inline void stage_tile(const float* __restrict__ src,
                                  unsigned short dst[][LDS_STRIDE], int tid) {
  const float4* s4 = reinterpret_cast<const float4*>(src);
#pragma unroll
  for (int i = 0; i < 16; ++i) {
    int f = i * 256 + tid;     // float4 index within the 128x128 tile
    int row = f >> 5;          // 32 float4 per row
    int c4 = (f & 31) * 4;
    float4 v = s4[f];
    ushort4 b;
    b.x = f2bf(v.x); b.y = f2bf(v.y); b.z = f2bf(v.z); b.w = f2bf(v.w);
    *reinterpret_cast<ushort4*>(&dst[row][c4]) = b;
  }
}

__global__ void zero_kernel(float* p, int n) {
  int i = blockIdx.x * blockDim.x + threadIdx.x;
  if (i < n) p[i] = 0.f;
}

// Main fused kernel: per row-block of 128 rows, sweep a 4096-column split in
// 128-wide tiles; accumulate per-row sum(exp) over all cols (ex-diag) and over
// positives (same label, ex-diag). bf16 MFMA 16x16x32 (verified layouts).
__global__ __launch_bounds__(256, 2) void cl_main(
    const float* __restrict__ emb, const int* __restrict__ labels,
    float* __restrict__ ws_all, float* __restrict__ ws_pos) {
  __shared__ unsigned short ldsA[BM][LDS_STRIDE];
  __shared__ unsigned short ldsB[BN][LDS_STRIDE];

  const int tid = threadIdx.x;
  const int lane = tid & 63;
  const int w = tid >> 6;        // wave 0..3, owns rows [w*32, w*32+32)
  const int col16 = lane & 15;   // MFMA col within 16-tile
  const int quad = lane >> 4;    // MFMA row group: rows quad*4 + reg
  const int r0 = blockIdx.x * BM;
  const int cs = blockIdx.y;

  stage_tile(emb + (size_t)r0 * DIM, ldsA, tid);
  __syncthreads();

  // Preload all A fragments for this wave's 32 rows; A never re-read from LDS.
  // A-frag layout (verified): lane holds A[m = lane&15][k = quad*8 + j], j=0..7
  bf16x8 afrag[2][4];
#pragma unroll
  for (int tr = 0; tr < 2; ++tr) {
    int row_a = w * 32 + tr * 16 + col16;
#pragma unroll
    for (int ks = 0; ks < 4; ++ks)
      afrag[tr][ks] =
          *reinterpret_cast<const bf16x8*>(&ldsA[row_a][ks * 32 + quad * 8]);
  }

  // Row labels + per-lane row partial sums (C/D rows this lane owns).
  int labi[8];
  float all_p[8], pos_p[8];
#pragma unroll
  for (int tr = 0; tr < 2; ++tr)
#pragma unroll
    for (int r = 0; r < 4; ++r) {
      labi[tr * 4 + r] = labels[r0 + w * 32 + tr * 16 + quad * 4 + r];
      all_p[tr * 4 + r] = 0.f;
      pos_p[tr * 4 + r] = 0.f;
    }

  const float SCALE = 2.8853900817779268f;  // (1/T)*log2(e), T=0.5

  for (int ct = 0; ct < CPS / BN; ++ct) {
    const int c0 = cs * CPS + ct * BN;
    __syncthreads();  // previous tile's compute done before overwrite
    stage_tile(emb + (size_t)c0 * DIM, ldsB, tid);
    __syncthreads();

#pragma unroll
    for (int tc = 0; tc < 8; ++tc) {
      // B-frag layout: lane holds B[k = quad*8 + j][n = lane&15] == E[col][k]
      bf16x8 bf[4];
      int rowb = tc * 16 + col16;
#pragma unroll
      for (int ks = 0; ks < 4; ++ks)
        bf[ks] =
            *reinterpret_cast<const bf16x8*>(&ldsB[rowb][ks * 32 + quad * 8]);
      int jg = c0 + tc * 16 + col16;  // this lane's global column
      int labj = labels[jg];
#pragma unroll
      for (int tr = 0; tr < 2; ++tr) {
        f32x4 acc = {0.f, 0.f, 0.f, 0.f};
#pragma unroll
        for (int ks = 0; ks < 4; ++ks)
          acc = __builtin_amdgcn_mfma_f32_16x16x32_bf16(afrag[tr][ks], bf[ks],
                                                        acc, 0, 0, 0);
        // C/D layout (m89/m91-verified): col=lane&15, row=quad*4+reg
        const bool diag = (c0 + tc * 16) == (r0 + w * 32 + tr * 16);
#pragma unroll
        for (int r = 0; r < 4; ++r) {
          float e = fast_exp2(acc[r] * SCALE);
          if (diag && (quad * 4 + r) == col16) e = 0.f;  // exclude j == i
          all_p[tr * 4 + r] += e;
          pos_p[tr * 4 + r] += (labi[tr * 4 + r] == labj) ? e : 0.f;
        }
      }
    }
  }

  // Sum over the 16 lanes (col16) that share each row, then one atomic per row.
#pragma unroll
  for (int t = 0; t < 8; ++t) {
    float a = all_p[t], p = pos_p[t];
#pragma unroll
    for (int m = 8; m >= 1; m >>= 1) {
      a += __shfl_xor(a, m, 64);
      p += __shfl_xor(p, m, 64);
    }
    if (col16 == 0) {
      int row_g = r0 + w * 32 + (t >> 2) * 16 + quad * 4 + (t & 3);
      atomicAdd(&ws_all[row_g], a);
      atomicAdd(&ws_pos[row_g], p);
    }
  }
}

__global__ void finalize_kernel(const float* __restrict__ ws_all,
                                const float* __restrict__ ws_pos,
                                float* __restrict__ out) {
  __shared__ float s_t[256];
  __shared__ int s_c[256];
  const int tid = threadIdx.x;
  float tot = 0.f;
  int cnt = 0;
  for (int i = tid; i < N_EMB; i += 256) {
    float p = ws_pos[i];
    if (p > 0.f) {
      float a = ws_all[i];
      // loss_i = ln(all) - ln(pos) = (log2(all)-log2(pos)) * ln2
      tot += (fast_log2(a) - fast_log2(p)) * 0.6931471805599453f;
      cnt++;
    }
  }
  s_t[tid] = tot;
  s_c[tid] = cnt;
  __syncthreads();
  for (int s = 128; s > 0; s >>= 1) {
    if (tid < s) {
      s_t[tid] += s_t[tid + s];
      s_c[tid] += s_c[tid + s];
    }
    __syncthreads();
  }
  if (tid == 0) out[0] = (s_c[0] > 0) ? (s_t[0] / (float)s_c[0]) : 0.f;
}

extern "C" void kernel_launch(void* const* d_in, const int* in_sizes, int n_in,
                              void* d_out, int out_size, void* d_ws,
                              size_t ws_size, hipStream_t stream) {
  const float* emb = (const float*)d_in[0];
  const int* labels = (const int*)d_in[1];
  float* ws_all = (float*)d_ws;
  float* ws_pos = ws_all + N_EMB;

  // ws is re-poisoned before every timed call: zero the accumulators first.
  zero_kernel<<<(2 * N_EMB + 255) / 256, 256, 0, stream>>>(ws_all, 2 * N_EMB);
  cl_main<<<dim3(BM == 128 ? N_EMB / BM : 0, NSPLIT), 256, 0, stream>>>(
      emb, labels, ws_all, ws_pos);
  finalize_kernel<<<1, 256, 0, stream>>>(ws_all, ws_pos, (float*)d_out);
}

// Round 2
// 209.260 us; speedup vs baseline: 1.0362x; 1.0362x over previous
//
#include <hip/hip_runtime.h>

#define N_EMB 16384
#define DIM 128
#define BM 128
#define BN 128
#define NSPLIT 8
#define CPS (N_EMB / NSPLIT)  /* 2048 cols per split */
#define NCT (CPS / BN)        /* 16 column tiles per block */

typedef __bf16 bf16x8 __attribute__((ext_vector_type(8)));
typedef float f32x4 __attribute__((ext_vector_type(4)));
typedef unsigned short us8 __attribute__((ext_vector_type(8)));

__device__ inline float fast_exp2(float x) {
#if __has_builtin(__builtin_amdgcn_exp2f)
  return __builtin_amdgcn_exp2f(x);
#else
  return exp2f(x);
#endif
}
__device__ inline float fast_log2(float x) {
#if __has_builtin(__builtin_amdgcn_logf)
  return __builtin_amdgcn_logf(x);
#else
  return log2f(x);
#endif
}

// fp32 -> bf16 RNE (finite inputs)
__device__ inline unsigned short f2bf(float f) {
  unsigned int u = __float_as_uint(f);
  u += 0x7fffu + ((u >> 16) & 1u);
  return (unsigned short)(u >> 16);
}

// Fragment-linear LDS layout for a 128x128 tile (rows x dims), bf16.
// Granule G = tc*256 + ks*64 + quad*16 + col16 holds 8 bf16 of
// src[(tc*16+col16)*DIM + ks*32 + quad*8 .. +7].
// MFMA fragment read for (tile16 tc, ks): byte addr = (tc*4+ks)*1024 + lane*16
// -> lane-contiguous 16B reads, conflict-free. Staging writes are G-linear
// across threads -> also lane-contiguous.
template <bool SCALED>
__device__ inline void stage_tile_fl(const float* __restrict__ src,
                                     unsigned short* __restrict__ dst, int tid,
                                     float scale) {
#pragma unroll
  for (int i = 0; i < 8; ++i) {
    int G = i * 256 + tid;
    int col16 = G & 15;
    int quad = (G >> 4) & 3;
    int ks = (G >> 6) & 3;
    int tc = G >> 8;
    const float* p = src + (tc * 16 + col16) * DIM + ks * 32 + quad * 8;
    float4 a = *reinterpret_cast<const float4*>(p);
    float4 b = *reinterpret_cast<const float4*>(p + 4);
    if (SCALED) {
      a.x *= scale; a.y *= scale; a.z *= scale; a.w *= scale;
      b.x *= scale; b.y *= scale; b.z *= scale; b.w *= scale;
    }
    us8 g;
    g[0] = f2bf(a.x); g[1] = f2bf(a.y); g[2] = f2bf(a.z); g[3] = f2bf(a.w);
    g[4] = f2bf(b.x); g[5] = f2bf(b.y); g[6] = f2bf(b.z); g[7] = f2bf(b.w);
    *reinterpret_cast<us8*>(dst + G * 8) = g;  // one ds_write_b128
  }
}

// Per row-block of 128 rows x one 2048-col split: exp-sim row partials.
// A is pre-scaled by (1/T)*log2(e) so epilogue is exp2(acc) directly.
// ws partials: ws_all[cs*N + row], ws_pos[cs*N + row] — no atomics, no zeroing.
__global__ __launch_bounds__(256, 4) void cl_main(
    const float* __restrict__ emb, const int* __restrict__ labels,
    float* __restrict__ ws_all, float* __restrict__ ws_pos) {
  __shared__ unsigned short lds[BN * DIM];  // 32 KB: A during preload, then B

  const int tid = threadIdx.x;
  const int lane = tid & 63;
  const int w = tid >> 6;       // wave 0..3, owns rows [w*32, w*32+32)
  const int col16 = lane & 15;  // MFMA col (and frag row) index
  const int quad = lane >> 4;
  const int r0 = blockIdx.x * BM;
  const int cs = blockIdx.y;

  const float SCALE = 2.8853900817779268f;  // (1/T)*log2(e), T=0.5

  stage_tile_fl<true>(emb + (size_t)r0 * DIM, lds, tid, SCALE);
  __syncthreads();

  // Preload A fragments for this wave's 32 rows (A never re-read from LDS).
  // A-frag: lane holds A[m = lane&15][k = quad*8 + j], j=0..7 (verified R1).
  bf16x8 afrag[2][4];
#pragma unroll
  for (int tr = 0; tr < 2; ++tr)
#pragma unroll
    for (int ks = 0; ks < 4; ++ks)
      afrag[tr][ks] = *reinterpret_cast<const bf16x8*>(
          lds + ((w * 2 + tr) * 4 + ks) * 512 + lane * 8);

  int labi[8];
  float all_p[8], pos_p[8];
#pragma unroll
  for (int t = 0; t < 8; ++t) {
    labi[t] = labels[r0 + w * 32 + (t >> 2) * 16 + quad * 4 + (t & 3)];
    all_p[t] = 0.f;
    pos_p[t] = 0.f;
  }

  for (int ct = 0; ct < NCT; ++ct) {
    const int c0 = cs * CPS + ct * BN;
    __syncthreads();  // prior compute (or A preload) done before overwrite
    stage_tile_fl<false>(emb + (size_t)c0 * DIM, lds, tid, 1.f);
    __syncthreads();

    int labj[8];
#pragma unroll
    for (int tc = 0; tc < 8; ++tc) labj[tc] = labels[c0 + tc * 16 + col16];

#pragma unroll
    for (int tc = 0; tc < 8; ++tc) {
      bf16x8 bf[4];
#pragma unroll
      for (int ks = 0; ks < 4; ++ks)
        bf[ks] = *reinterpret_cast<const bf16x8*>(lds + (tc * 4 + ks) * 512 +
                                                  lane * 8);
#pragma unroll
      for (int tr = 0; tr < 2; ++tr) {
        f32x4 acc = {0.f, 0.f, 0.f, 0.f};
#pragma unroll
        for (int ks = 0; ks < 4; ++ks)
          acc = __builtin_amdgcn_mfma_f32_16x16x32_bf16(afrag[tr][ks], bf[ks],
                                                        acc, 0, 0, 0);
        // C/D layout (verified): col = lane&15, row = quad*4 + r
        const bool diag = (c0 + tc * 16) == (r0 + w * 32 + tr * 16);
#pragma unroll
        for (int r = 0; r < 4; ++r) {
          float e = fast_exp2(acc[r]);
          if (diag && (quad * 4 + r) == col16) e = 0.f;  // exclude j == i
          all_p[tr * 4 + r] += e;
          pos_p[tr * 4 + r] += (labi[tr * 4 + r] == labj[tc]) ? e : 0.f;
        }
      }
    }
  }

  // Reduce across the 16 col-lanes sharing each row; one plain store per row.
#pragma unroll
  for (int t = 0; t < 8; ++t) {
    float a = all_p[t], p = pos_p[t];
#pragma unroll
    for (int m = 8; m >= 1; m >>= 1) {
      a += __shfl_xor(a, m, 64);
      p += __shfl_xor(p, m, 64);
    }
    if (col16 == 0) {
      int row_g = r0 + w * 32 + (t >> 2) * 16 + quad * 4 + (t & 3);
      ws_all[cs * N_EMB + row_g] = a;
      ws_pos[cs * N_EMB + row_g] = p;
    }
  }
}

__global__ __launch_bounds__(1024) void finalize_kernel(
    const float* __restrict__ ws_all, const float* __restrict__ ws_pos,
    float* __restrict__ out) {
  __shared__ float s_t[1024];
  __shared__ int s_c[1024];
  const int tid = threadIdx.x;
  float tot = 0.f;
  int cnt = 0;
  for (int row = tid; row < N_EMB; row += 1024) {
    float a = 0.f, p = 0.f;
#pragma unroll
    for (int s = 0; s < NSPLIT; ++s) {
      a += ws_all[s * N_EMB + row];
      p += ws_pos[s * N_EMB + row];
    }
    if (p > 0.f) {
      tot += fast_log2(a) - fast_log2(p);
      cnt++;
    }
  }
  s_t[tid] = tot;
  s_c[tid] = cnt;
  __syncthreads();
  for (int s = 512; s > 0; s >>= 1) {
    if (tid < s) {
      s_t[tid] += s_t[tid + s];
      s_c[tid] += s_c[tid + s];
    }
    __syncthreads();
  }
  if (tid == 0)
    out[0] = (s_c[0] > 0) ? (s_t[0] * 0.6931471805599453f / (float)s_c[0]) : 0.f;
}

extern "C" void kernel_launch(void* const* d_in, const int* in_sizes, int n_in,
                              void* d_out, int out_size, void* d_ws,
                              size_t ws_size, hipStream_t stream) {
  const float* emb = (const float*)d_in[0];
  const int* labels = (const int*)d_in[1];
  float* ws_all = (float*)d_ws;                 // [NSPLIT][N_EMB]
  float* ws_pos = ws_all + NSPLIT * N_EMB;      // [NSPLIT][N_EMB]

  cl_main<<<dim3(N_EMB / BM, NSPLIT), 256, 0, stream>>>(emb, labels, ws_all,
                                                        ws_pos);
  finalize_kernel<<<1, 1024, 0, stream>>>(ws_all, ws_pos, (float*)d_out);
}

// Round 3
// 164.572 us; speedup vs baseline: 1.3176x; 1.2715x over previous
//
#include <hip/hip_runtime.h>

#define N_EMB 16384
#define DIM 128
#define BM 128
#define BN 128
#define NSPLIT 8
#define CPS (N_EMB / NSPLIT)  /* 2048 cols per split */
#define NCT (CPS / BN)        /* 16 column tiles per block */

typedef __bf16 bf16x8 __attribute__((ext_vector_type(8)));
typedef float f32x4 __attribute__((ext_vector_type(4)));
typedef unsigned short us8 __attribute__((ext_vector_type(8)));
typedef unsigned int u32;

#define SCALE 2.8853900817779268f /* (1/T)*log2(e), T=0.5 */

__device__ inline float fast_exp2(float x) {
#if __has_builtin(__builtin_amdgcn_exp2f)
  return __builtin_amdgcn_exp2f(x);
#else
  return exp2f(x);
#endif
}
__device__ inline float fast_log2(float x) {
#if __has_builtin(__builtin_amdgcn_logf)
  return __builtin_amdgcn_logf(x);
#else
  return log2f(x);
#endif
}

// fp32 -> bf16 RNE (finite inputs)
__device__ inline unsigned short f2bf(float f) {
  unsigned int u = __float_as_uint(f);
  u += 0x7fffu + ((u >> 16) & 1u);
  return (unsigned short)(u >> 16);
}

// global->LDS DMA, 16 B per lane. LDS dest = wave-uniform base + lane*16.
__device__ inline void gll16(const unsigned short* g, unsigned short* l) {
  __builtin_amdgcn_global_load_lds(
      (const __attribute__((address_space(1))) u32*)g,
      (__attribute__((address_space(3))) u32*)l, 16, 0, 0);
}

// Fragment-linear order for a 128-row x 128-dim tile of bf16:
// granule G = tc*256 + ks*64 + quad*16 + col16 holds 8 bf16 of
// row (tc*16+col16), dims ks*32+quad*8 .. +7, stored at element G*8+j.
// MFMA fragment (tc,ks) then lives at byte (tc*4+ks)*1024 + lane*16,
// lane = quad*16+col16 — lane-contiguous, conflict-free, DMA-compatible.
__device__ inline void stage_tile_fl(const float* __restrict__ src,
                                     unsigned short* __restrict__ dst,
                                     int tid) {
#pragma unroll
  for (int i = 0; i < 8; ++i) {
    int G = i * 256 + tid;
    int col16 = G & 15;
    int quad = (G >> 4) & 3;
    int ks = (G >> 6) & 3;
    int tc = G >> 8;
    const float* p = src + (tc * 16 + col16) * DIM + ks * 32 + quad * 8;
    float4 a = *reinterpret_cast<const float4*>(p);
    float4 b = *reinterpret_cast<const float4*>(p + 4);
    us8 g;
    g[0] = f2bf(a.x); g[1] = f2bf(a.y); g[2] = f2bf(a.z); g[3] = f2bf(a.w);
    g[4] = f2bf(b.x); g[5] = f2bf(b.y); g[6] = f2bf(b.z); g[7] = f2bf(b.w);
    *reinterpret_cast<us8*>(dst + G * 8) = g;
  }
}

// One-time fp32 -> bf16 conversion into fragment-linear global layout.
// eraw = unscaled (B operand), escal = pre-scaled by SCALE (A operand).
__global__ __launch_bounds__(256) void preconv(
    const float* __restrict__ emb, unsigned short* __restrict__ eraw,
    unsigned short* __restrict__ escal) {
  __shared__ unsigned short lds[128 * DIM];
  const int tid = threadIdx.x;
  const size_t base = (size_t)blockIdx.x * (128 * DIM);
  stage_tile_fl(emb + base, lds, tid);
  __syncthreads();
#pragma unroll
  for (int i = 0; i < 8; ++i) {
    int G = i * 256 + tid;
    us8 v = *reinterpret_cast<const us8*>(lds + G * 8);
    *reinterpret_cast<us8*>(eraw + base + G * 8) = v;
    us8 s;
#pragma unroll
    for (int j = 0; j < 8; ++j) {
      float f = __uint_as_float((u32)v[j] << 16) * SCALE;
      s[j] = f2bf(f);
    }
    *reinterpret_cast<us8*>(escal + base + G * 8) = s;
  }
}

// Main fused kernel. A tile (pre-scaled) staged once via DMA, fragments live
// in registers for the whole kernel; B tiles DMA'd per iteration; epilogue is
// exp2(acc) + masked accumulate. No staging VALU, no ds_write, no atomics.
__global__ __launch_bounds__(256, 4) void cl_main(
    const unsigned short* __restrict__ eraw,
    const unsigned short* __restrict__ escal,
    const int* __restrict__ labels, float* __restrict__ ws_all,
    float* __restrict__ ws_pos) {
  __shared__ unsigned short lds[BN * DIM];  // 32 KB, A then B

  const int tid = threadIdx.x;
  const int lane = tid & 63;
  const int w = tid >> 6;       // wave 0..3, owns rows [w*32, w*32+32)
  const int col16 = lane & 15;
  const int quad = lane >> 4;
  const int r0 = blockIdx.x * BM;
  const int cs = blockIdx.y;

  // Stage scaled A tile (32 KB): 8 DMA instrs per thread, 1 KB/wave each.
  {
    const unsigned short* g = escal + (size_t)r0 * DIM;
#pragma unroll
    for (int i = 0; i < 8; ++i) {
      int chunk = i * 4 + w;
      gll16(g + chunk * 512 + lane * 8, lds + chunk * 512);
    }
  }
  __syncthreads();

  // A-frag (verified): lane holds A[m=lane&15][k=quad*8+j], j=0..7.
  bf16x8 afrag[2][4];
#pragma unroll
  for (int tr = 0; tr < 2; ++tr)
#pragma unroll
    for (int ks = 0; ks < 4; ++ks)
      afrag[tr][ks] = *reinterpret_cast<const bf16x8*>(
          lds + ((w * 2 + tr) * 4 + ks) * 512 + lane * 8);

  int labi[8];
  float all_p[8], pos_p[8];
#pragma unroll
  for (int t = 0; t < 8; ++t) {
    labi[t] = labels[r0 + w * 32 + (t >> 2) * 16 + quad * 4 + (t & 3)];
    all_p[t] = 0.f;
    pos_p[t] = 0.f;
  }

  for (int ct = 0; ct < NCT; ++ct) {
    const int c0 = cs * CPS + ct * BN;
    __syncthreads();  // prior compute (or afrag preload) done before overwrite
    {
      const unsigned short* g = eraw + (size_t)c0 * DIM;
#pragma unroll
      for (int i = 0; i < 8; ++i) {
        int chunk = i * 4 + w;
        gll16(g + chunk * 512 + lane * 8, lds + chunk * 512);
      }
    }
    __syncthreads();  // vmcnt(0) drained before barrier -> B tile visible

#pragma unroll
    for (int tc = 0; tc < 8; ++tc) {
      bf16x8 bf[4];
#pragma unroll
      for (int ks = 0; ks < 4; ++ks)
        bf[ks] = *reinterpret_cast<const bf16x8*>(lds + (tc * 4 + ks) * 512 +
                                                  lane * 8);
      int labj = labels[c0 + tc * 16 + col16];
#pragma unroll
      for (int tr = 0; tr < 2; ++tr) {
        f32x4 acc = {0.f, 0.f, 0.f, 0.f};
#pragma unroll
        for (int ks = 0; ks < 4; ++ks)
          acc = __builtin_amdgcn_mfma_f32_16x16x32_bf16(afrag[tr][ks], bf[ks],
                                                        acc, 0, 0, 0);
        // C/D layout (verified): col = lane&15, row = quad*4 + r
        const bool diag = (c0 + tc * 16) == (r0 + w * 32 + tr * 16);
#pragma unroll
        for (int r = 0; r < 4; ++r) {
          float e = fast_exp2(acc[r]);
          if (diag && (quad * 4 + r) == col16) e = 0.f;  // exclude j == i
          all_p[tr * 4 + r] += e;
          pos_p[tr * 4 + r] += (labi[tr * 4 + r] == labj) ? e : 0.f;
        }
      }
    }
  }

  // Reduce across the 16 col-lanes sharing each row; plain store per row.
#pragma unroll
  for (int t = 0; t < 8; ++t) {
    float a = all_p[t], p = pos_p[t];
#pragma unroll
    for (int m = 8; m >= 1; m >>= 1) {
      a += __shfl_xor(a, m, 64);
      p += __shfl_xor(p, m, 64);
    }
    if (col16 == 0) {
      int row_g = r0 + w * 32 + (t >> 2) * 16 + quad * 4 + (t & 3);
      ws_all[cs * N_EMB + row_g] = a;
      ws_pos[cs * N_EMB + row_g] = p;
    }
  }
}

__global__ __launch_bounds__(1024) void finalize_kernel(
    const float* __restrict__ ws_all, const float* __restrict__ ws_pos,
    float* __restrict__ out) {
  __shared__ float s_t[1024];
  __shared__ int s_c[1024];
  const int tid = threadIdx.x;
  float tot = 0.f;
  int cnt = 0;
  for (int row = tid; row < N_EMB; row += 1024) {
    float a = 0.f, p = 0.f;
#pragma unroll
    for (int s = 0; s < NSPLIT; ++s) {
      a += ws_all[s * N_EMB + row];
      p += ws_pos[s * N_EMB + row];
    }
    if (p > 0.f) {
      tot += fast_log2(a) - fast_log2(p);
      cnt++;
    }
  }
  s_t[tid] = tot;
  s_c[tid] = cnt;
  __syncthreads();
  for (int s = 512; s > 0; s >>= 1) {
    if (tid < s) {
      s_t[tid] += s_t[tid + s];
      s_c[tid] += s_c[tid + s];
    }
    __syncthreads();
  }
  if (tid == 0)
    out[0] =
        (s_c[0] > 0) ? (s_t[0] * 0.6931471805599453f / (float)s_c[0]) : 0.f;
}

extern "C" void kernel_launch(void* const* d_in, const int* in_sizes, int n_in,
                              void* d_out, int out_size, void* d_ws,
                              size_t ws_size, hipStream_t stream) {
  const float* emb = (const float*)d_in[0];
  const int* labels = (const int*)d_in[1];

  unsigned short* eraw = (unsigned short*)d_ws;          // 4 MB bf16 frag-linear
  unsigned short* escal = eraw + (size_t)N_EMB * DIM;    // 4 MB pre-scaled
  float* ws_all = (float*)(escal + (size_t)N_EMB * DIM); // [NSPLIT][N]
  float* ws_pos = ws_all + NSPLIT * N_EMB;               // [NSPLIT][N]

  preconv<<<N_EMB / 128, 256, 0, stream>>>(emb, eraw, escal);
  cl_main<<<dim3(N_EMB / BM, NSPLIT), 256, 0, stream>>>(eraw, escal, labels,
                                                        ws_all, ws_pos);
  finalize_kernel<<<1, 1024, 0, stream>>>(ws_all, ws_pos, (float*)d_out);
}